// Round 1
// baseline (19931.476 us; speedup 1.0000x reference)
//
#include <hip/hip_runtime.h>

#define BDIM 256   // batch
#define SDIM 512   // seq len
#define HDIM 512   // hidden
#define VDIM 128   // vocab
#define NBG 8      // batch groups
#define BB 32      // batch per group
#define NHS 32     // hidden slices
#define HHU 16     // hidden units per block
#define KP 520     // padded LDS pitch for K=512 (bf16 elems)
#define WIHP 136   // padded pitch for W_ih slice
#define NT 320     // threads per block (5 waves)

typedef unsigned short ushort_t;
typedef __attribute__((ext_vector_type(8))) short bf16x8;
typedef __attribute__((ext_vector_type(4))) float f32x4;

__device__ __forceinline__ ushort_t f2bf(float x) {
  unsigned u = __builtin_bit_cast(unsigned, x);
  u += 0x7fffu + ((u >> 16) & 1u);
  return (ushort_t)(u >> 16);
}
__device__ __forceinline__ float bf2f(ushort_t b) {
  unsigned u = ((unsigned)b) << 16;
  return __builtin_bit_cast(float, u);
}
__device__ __forceinline__ float sigmoidf_(float x) { return 1.f / (1.f + __expf(-x)); }
__device__ __forceinline__ float tanhf_(float x) { return 2.f / (1.f + __expf(-2.f * x)) - 1.f; }

__device__ __forceinline__ void pack_store8(ushort_t* dst, const float* s) {
  ushort_t tmp[8];
#pragma unroll
  for (int j = 0; j < 8; ++j) tmp[j] = f2bf(s[j]);
  uint4 v;
  v.x = (unsigned)tmp[0] | ((unsigned)tmp[1] << 16);
  v.y = (unsigned)tmp[2] | ((unsigned)tmp[3] << 16);
  v.z = (unsigned)tmp[4] | ((unsigned)tmp[5] << 16);
  v.w = (unsigned)tmp[6] | ((unsigned)tmp[7] << 16);
  *(uint4*)dst = v;
}

// Load this block's 64 gate rows (i,f,g,o for its 16 units) of W_hh/W_ih + biases.
__device__ __forceinline__ void load_lstm_w(ushort_t* Whh_s, ushort_t* Wih_s, float* bias_s,
                                            const float* Wih, const float* Whh,
                                            const float* bi, const float* bh,
                                            int hs, int tid) {
  for (int c = tid; c < 64 * 64; c += NT) {  // 64 rows x 512 cols, 8-float chunks
    int r = c >> 6, k8 = (c & 63) * 8;
    int gr = (r >> 4) * HDIM + hs * HHU + (r & 15);
    pack_store8(&Whh_s[r * KP + k8], Whh + (size_t)gr * HDIM + k8);
  }
  for (int c = tid; c < 64 * 16; c += NT) {  // 64 rows x 128 cols
    int r = c >> 4, k8 = (c & 15) * 8;
    int gr = (r >> 4) * HDIM + hs * HHU + (r & 15);
    pack_store8(&Wih_s[r * WIHP + k8], Wih + (size_t)gr * VDIM + k8);
  }
  if (tid < 64) {
    int gr = (tid >> 4) * HDIM + hs * HHU + (tid & 15);
    bias_s[tid] = bi[gr] + bh[gr];
  }
}

__global__ void __launch_bounds__(NT) lstm_kernel(
    const int* __restrict__ C_idx, const int* __restrict__ E,
    const float* __restrict__ eWih, const float* __restrict__ eWhh,
    const float* __restrict__ ebi, const float* __restrict__ ebh,
    const float* __restrict__ dWih, const float* __restrict__ dWhh,
    const float* __restrict__ dbi, const float* __restrict__ dbh,
    const float* __restrict__ pW, const float* __restrict__ pb,
    unsigned* cnt, ushort_t* hbuf, ushort_t* logits) {
  __shared__ ushort_t Whh_s[80 * KP];    // rows 0..63: gates; rows 64..79: proj (decoder)
  __shared__ ushort_t Wih_s[64 * WIHP];
  __shared__ ushort_t h_s[32 * KP];
  __shared__ float g_s[4 * BB * 17];
  __shared__ float c_s[BB * 17];
  __shared__ float bias_s[64];
  __shared__ float pb_s[4];
  __shared__ int idx_s[BB];

  const int tid = threadIdx.x;
  const int w = tid >> 6;
  const int lane = tid & 63;
  const int bg = blockIdx.x & 7;    // bg = blockIdx % 8 -> one bg per XCD under round-robin
  const int hs = blockIdx.x >> 3;

  load_lstm_w(Whh_s, Wih_s, bias_s, eWih, eWhh, ebi, ebh, hs, tid);
  for (int i = tid; i < BB * 17; i += NT) c_s[i] = 0.f;
  __syncthreads();

  for (int t = 0; t <= 1024; ++t) {
    const bool last = (t == 1024);
    if (t == 512) {
      // phase switch: decoder weights + projection rows 64..67
      load_lstm_w(Whh_s, Wih_s, bias_s, dWih, dWhh, dbi, dbh, hs, tid);
      for (int c = tid; c < 4 * 64; c += NT) {
        int r = c >> 6, k8 = (c & 63) * 8;
        pack_store8(&Whh_s[(64 + r) * KP + k8], pW + (size_t)(hs * 4 + r) * HDIM + k8);
      }
      if (tid < 4) pb_s[tid] = pb[hs * 4 + tid];
    }
    if (!last && tid < BB) {
      idx_s[tid] = (t >= 512) ? E[(size_t)(bg * BB + tid) * (SDIM + 1) + (t - 512)]
                              : C_idx[(size_t)(bg * BB + tid) * SDIM + t];
    }
    if (t > 0 && tid == 0) {
      int spins = 0;
      while (__hip_atomic_load(&cnt[(t - 1) * NBG + bg], __ATOMIC_RELAXED,
                               __HIP_MEMORY_SCOPE_AGENT) < 32u) {
        __builtin_amdgcn_s_sleep(1);
        if (++spins > (1 << 18)) break;  // deadlock bailout (never hit if co-resident)
      }
    }
    __syncthreads();
    __builtin_amdgcn_fence(__ATOMIC_ACQUIRE, "agent");  // invalidate stale L1/L2 lines

    // stage h[32,512] bf16 (32 KB) -> LDS (padded pitch), batched loads then stores
    {
      const uint4* src = (const uint4*)(hbuf + ((size_t)(t & 1) * BDIM + bg * BB) * HDIM);
      uint4 tmp[7];
#pragma unroll
      for (int k = 0; k < 7; ++k) {
        int c = tid + k * NT;
        if (c < 2048) tmp[k] = src[c];
      }
#pragma unroll
      for (int k = 0; k < 7; ++k) {
        int c = tid + k * NT;
        if (c < 2048) {
          int r = c >> 6, k8 = (c & 63) * 8;
          *(uint4*)&h_s[r * KP + k8] = tmp[k];
        }
      }
    }
    __syncthreads();

    const bool proj_on = (t >= 513);
    const int u = lane & 15, q = lane >> 4;
    if ((w < 4 && !last) || (w == 4 && proj_on)) {
      f32x4 acc0 = {0.f, 0.f, 0.f, 0.f};
      f32x4 acc1 = {0.f, 0.f, 0.f, 0.f};
      if (w < 4) {
        // acc init = bias + one-hot gather from W_ih
        float bv = bias_s[w * HHU + u];
        const int rowoff = (w * HHU + u) * WIHP;
#pragma unroll
        for (int r = 0; r < 4; ++r) acc0[r] = bv + bf2f(Wih_s[rowoff + idx_s[q * 4 + r]]);
#pragma unroll
        for (int r = 0; r < 4; ++r) acc1[r] = bv + bf2f(Wih_s[rowoff + idx_s[16 + q * 4 + r]]);
      }
      const ushort_t* bp = &Whh_s[(w * 16 + u) * KP + q * 8];
      const ushort_t* ap0 = &h_s[u * KP + q * 8];
      const ushort_t* ap1 = &h_s[(16 + u) * KP + q * 8];
#pragma unroll
      for (int kt = 0; kt < 16; ++kt) {
        bf16x8 bfr = *(const bf16x8*)(bp + kt * 32);
        bf16x8 af0 = *(const bf16x8*)(ap0 + kt * 32);
        bf16x8 af1 = *(const bf16x8*)(ap1 + kt * 32);
        acc0 = __builtin_amdgcn_mfma_f32_16x16x32_bf16(af0, bfr, acc0, 0, 0, 0);
        acc1 = __builtin_amdgcn_mfma_f32_16x16x32_bf16(af1, bfr, acc1, 0, 0, 0);
      }
      if (w < 4) {
#pragma unroll
        for (int r = 0; r < 4; ++r) {
          g_s[(w * BB + q * 4 + r) * 17 + u] = acc0[r];
          g_s[(w * BB + 16 + q * 4 + r) * 17 + u] = acc1[r];
        }
      } else if (u < 4) {
        const int ld = t - 513;  // logits step index 0..511
        float pbv = pb_s[u];
#pragma unroll
        for (int r = 0; r < 4; ++r) {
          logits[((size_t)ld * BDIM + bg * BB + q * 4 + r) * VDIM + hs * 4 + u] =
              f2bf(acc0[r] + pbv);
          logits[((size_t)ld * BDIM + bg * BB + 16 + q * 4 + r) * VDIM + hs * 4 + u] =
              f2bf(acc1[r] + pbv);
        }
      }
    }
    __syncthreads();

    if (!last) {
      if (tid < 128) {  // c/h update: 32 batches x 16 units, 4 units/thread
        const int b = tid >> 2, uq = tid & 3;
        ushort_t hv[4];
#pragma unroll
        for (int j = 0; j < 4; ++j) {
          const int uu = uq * 4 + j;
          float ig = g_s[(0 * BB + b) * 17 + uu];
          float fg = g_s[(1 * BB + b) * 17 + uu];
          float gg = g_s[(2 * BB + b) * 17 + uu];
          float og = g_s[(3 * BB + b) * 17 + uu];
          float co = c_s[b * 17 + uu];
          float cn = sigmoidf_(fg) * co + sigmoidf_(ig) * tanhf_(gg);
          c_s[b * 17 + uu] = cn;
          hv[j] = f2bf(sigmoidf_(og) * tanhf_(cn));
        }
        unsigned long long pk = (unsigned long long)hv[0] |
                                ((unsigned long long)hv[1] << 16) |
                                ((unsigned long long)hv[2] << 32) |
                                ((unsigned long long)hv[3] << 48);
        *(unsigned long long*)(hbuf + ((size_t)((t + 1) & 1) * BDIM + bg * BB + b) * HDIM +
                               hs * HHU + uq * 4) = pk;
      }
      __syncthreads();  // drains vmcnt(0): h stores are in L2 before flag
      if (tid == 0)
        __hip_atomic_fetch_add(&cnt[t * NBG + bg], 1u, __ATOMIC_RELEASE,
                               __HIP_MEMORY_SCOPE_AGENT);  // release: wbl2 -> LLC
    }
  }
}

__global__ void loss_kernel(const ushort_t* __restrict__ logits, const int* __restrict__ E,
                            float* __restrict__ partial) {
  const int t = blockIdx.x;   // 512
  const int b = threadIdx.x;  // 256
  const ushort_t* row = logits + ((size_t)t * BDIM + b) * VDIM;
  float mx = -3.0e38f;
  for (int k = 0; k < VDIM; ++k) mx = fmaxf(mx, bf2f(row[k]));
  float se = 0.f;
  for (int k = 0; k < VDIM; ++k) se += __expf(bf2f(row[k]) - mx);
  const int tgt = E[(size_t)b * (SDIM + 1) + t];
  float nll = (mx + __logf(se)) - bf2f(row[tgt]);
  float m = (tgt != 0) ? 1.f : 0.f;
  __shared__ float s1[BDIM];
  __shared__ float s0[BDIM];
  s1[b] = nll * m;
  s0[b] = m;
  __syncthreads();
  for (int s = 128; s > 0; s >>= 1) {
    if (b < s) {
      s1[b] += s1[b + s];
      s0[b] += s0[b + s];
    }
    __syncthreads();
  }
  if (b == 0) partial[t] = (s0[0] > 0.f) ? s1[0] / s0[0] : 0.f;
}

__global__ void reduce_kernel(const float* __restrict__ partial, float* __restrict__ out) {
  __shared__ float sm[SDIM];
  sm[threadIdx.x] = partial[threadIdx.x];
  __syncthreads();
  for (int s = 256; s > 0; s >>= 1) {
    if (threadIdx.x < s) sm[threadIdx.x] += sm[threadIdx.x + s];
    __syncthreads();
  }
  if (threadIdx.x == 0) out[0] = sm[0];
}

extern "C" void kernel_launch(void* const* d_in, const int* in_sizes, int n_in,
                              void* d_out, int out_size, void* d_ws, size_t ws_size,
                              hipStream_t stream) {
  const int* C_idx = (const int*)d_in[0];
  const int* E = (const int*)d_in[1];
  const float* eWih = (const float*)d_in[2];
  const float* eWhh = (const float*)d_in[3];
  const float* ebi = (const float*)d_in[4];
  const float* ebh = (const float*)d_in[5];
  const float* dWih = (const float*)d_in[6];
  const float* dWhh = (const float*)d_in[7];
  const float* dbi = (const float*)d_in[8];
  const float* dbh = (const float*)d_in[9];
  const float* pW = (const float*)d_in[10];
  const float* pb = (const float*)d_in[11];

  char* ws = (char*)d_ws;
  unsigned* cnt = (unsigned*)ws;                               // 1024*8*4      = 32768 B
  ushort_t* hbuf = (ushort_t*)(ws + 32768);                    // 2*256*512*2   = 524288 B
  ushort_t* logits = (ushort_t*)(ws + 32768 + 524288);         // 512*256*128*2 = 32 MiB
  float* partial = (float*)(ws + 32768 + 524288 + 33554432);   // 512*4 B

  // zero counters + h double-buffer (h0 = c0 = 0); ws is poisoned 0xAA each call
  hipMemsetAsync(d_ws, 0, 32768 + 524288, stream);
  lstm_kernel<<<256, NT, 0, stream>>>(C_idx, E, eWih, eWhh, ebi, ebh, dWih, dWhh, dbi, dbh,
                                      pW, pb, cnt, hbuf, logits);
  loss_kernel<<<512, 256, 0, stream>>>(logits, E, partial);
  reduce_kernel<<<1, 512, 0, stream>>>(partial, (float*)d_out);
}

// Round 2
// 3725.130 us; speedup vs baseline: 5.3505x; 5.3505x over previous
//
#include <hip/hip_runtime.h>

#define BDIM 256   // batch
#define SDIM 512   // seq len
#define HDIM 512   // hidden
#define VDIM 128   // vocab
#define NBG 8      // batch groups
#define BB 32      // batch per group
#define NHS 32     // hidden slices
#define HHU 16     // hidden units per block
#define KP 520     // padded LDS pitch for K=512 (bf16 elems)
#define WIHP 136   // padded pitch for W_ih slice
#define NT 320     // threads per block (5 waves)

typedef unsigned short ushort_t;
typedef unsigned long long u64_t;
typedef __attribute__((ext_vector_type(8))) short bf16x8;
typedef __attribute__((ext_vector_type(4))) float f32x4;

__device__ __forceinline__ ushort_t f2bf(float x) {
  unsigned u = __builtin_bit_cast(unsigned, x);
  u += 0x7fffu + ((u >> 16) & 1u);
  return (ushort_t)(u >> 16);
}
__device__ __forceinline__ float bf2f(ushort_t b) {
  unsigned u = ((unsigned)b) << 16;
  return __builtin_bit_cast(float, u);
}
__device__ __forceinline__ float sigmoidf_(float x) { return 1.f / (1.f + __expf(-x)); }
__device__ __forceinline__ float tanhf_(float x) { return 2.f / (1.f + __expf(-2.f * x)) - 1.f; }

__device__ __forceinline__ void pack_store8(ushort_t* dst, const float* s) {
  ushort_t tmp[8];
#pragma unroll
  for (int j = 0; j < 8; ++j) tmp[j] = f2bf(s[j]);
  uint4 v;
  v.x = (unsigned)tmp[0] | ((unsigned)tmp[1] << 16);
  v.y = (unsigned)tmp[2] | ((unsigned)tmp[3] << 16);
  v.z = (unsigned)tmp[4] | ((unsigned)tmp[5] << 16);
  v.w = (unsigned)tmp[6] | ((unsigned)tmp[7] << 16);
  *(uint4*)dst = v;
}

// Load this block's 64 gate rows (i,f,g,o for its 16 units) of W_hh/W_ih + biases.
__device__ __forceinline__ void load_lstm_w(ushort_t* Whh_s, ushort_t* Wih_s, float* bias_s,
                                            const float* Wih, const float* Whh,
                                            const float* bi, const float* bh,
                                            int hs, int tid) {
  for (int c = tid; c < 64 * 64; c += NT) {  // 64 rows x 512 cols, 8-float chunks
    int r = c >> 6, k8 = (c & 63) * 8;
    int gr = (r >> 4) * HDIM + hs * HHU + (r & 15);
    pack_store8(&Whh_s[r * KP + k8], Whh + (size_t)gr * HDIM + k8);
  }
  for (int c = tid; c < 64 * 16; c += NT) {  // 64 rows x 128 cols
    int r = c >> 4, k8 = (c & 15) * 8;
    int gr = (r >> 4) * HDIM + hs * HHU + (r & 15);
    pack_store8(&Wih_s[r * WIHP + k8], Wih + (size_t)gr * VDIM + k8);
  }
  if (tid < 64) {
    int gr = (tid >> 4) * HDIM + hs * HHU + (tid & 15);
    bias_s[tid] = bi[gr] + bh[gr];
  }
}

// Sync protocol (per-access LLC coherence, NO cache-wide fences):
//  - all cross-block data (hbuf) and flags use relaxed AGENT-scope atomics
//    -> sc0/sc1 flags, bypass non-coherent L1/XCD-L2, hit the coherent LLC.
//  - producer: h stores (sc1) -> __syncthreads (s_waitcnt vmcnt(0): stores
//    complete at LLC) -> flag store (sc1). Monotonic per-producer flag, no RMW.
//  - consumer: poll 32 flags (coalesced 128B sc1 load) -> __syncthreads ->
//    staged sc1 reads. No buffer_inv / buffer_wbl2 anywhere in the loop.
__global__ void __launch_bounds__(NT) lstm_kernel(
    const int* __restrict__ C_idx, const int* __restrict__ E,
    const float* __restrict__ eWih, const float* __restrict__ eWhh,
    const float* __restrict__ ebi, const float* __restrict__ ebh,
    const float* __restrict__ dWih, const float* __restrict__ dWhh,
    const float* __restrict__ dbi, const float* __restrict__ dbh,
    const float* __restrict__ pW, const float* __restrict__ pb,
    unsigned* flags, ushort_t* hbuf, ushort_t* logits) {
  __shared__ ushort_t Whh_s[80 * KP];    // rows 0..63: gates; rows 64..79: proj (decoder)
  __shared__ ushort_t Wih_s[64 * WIHP];
  __shared__ ushort_t h_s[32 * KP];
  __shared__ float g_s[4 * BB * 17];
  __shared__ float c_s[BB * 17];
  __shared__ float bias_s[64];
  __shared__ float pb_s[4];
  __shared__ int idx_s[BB];

  const int tid = threadIdx.x;
  const int w = tid >> 6;
  const int lane = tid & 63;
  const int bg = blockIdx.x & 7;    // bg = blockIdx % 8 -> one bg per XCD under round-robin
  const int hs = blockIdx.x >> 3;

  load_lstm_w(Whh_s, Wih_s, bias_s, eWih, eWhh, ebi, ebh, hs, tid);
  for (int i = tid; i < BB * 17; i += NT) c_s[i] = 0.f;
  __syncthreads();

  for (int t = 0; t <= 1024; ++t) {
    const bool last = (t == 1024);
    if (t == 512) {
      // phase switch: decoder weights + projection rows 64..67
      load_lstm_w(Whh_s, Wih_s, bias_s, dWih, dWhh, dbi, dbh, hs, tid);
      for (int c = tid; c < 4 * 64; c += NT) {
        int r = c >> 6, k8 = (c & 63) * 8;
        pack_store8(&Whh_s[(64 + r) * KP + k8], pW + (size_t)(hs * 4 + r) * HDIM + k8);
      }
      if (tid < 4) pb_s[tid] = pb[hs * 4 + tid];
    }
    if (!last && tid < BB) {
      idx_s[tid] = (t >= 512) ? E[(size_t)(bg * BB + tid) * (SDIM + 1) + (t - 512)]
                              : C_idx[(size_t)(bg * BB + tid) * SDIM + t];
    }
    // Wait for all 32 producers of this bg to have finished step t-1.
    if (t > 0 && w == 0 && lane < NHS) {
      int spins = 0;
      while (__hip_atomic_load(&flags[bg * NHS + lane], __ATOMIC_RELAXED,
                               __HIP_MEMORY_SCOPE_AGENT) < (unsigned)t) {
        __builtin_amdgcn_s_sleep(1);
        if (++spins > (1 << 20)) break;  // deadlock bailout (never hit if co-resident)
      }
    }
    __syncthreads();

    // stage h[32,512] bf16 (32 KB) -> LDS via LLC-coherent 8B loads
    {
      const u64_t* src = (const u64_t*)(hbuf + ((size_t)(t & 1) * BDIM + bg * BB) * HDIM);
      u64_t tmp[13];
#pragma unroll
      for (int k = 0; k < 13; ++k) {
        int c = tid + k * NT;
        if (c < 4096)
          tmp[k] = __hip_atomic_load(src + c, __ATOMIC_RELAXED, __HIP_MEMORY_SCOPE_AGENT);
      }
#pragma unroll
      for (int k = 0; k < 13; ++k) {
        int c = tid + k * NT;
        if (c < 4096) {
          int r = c >> 7, k4 = (c & 127) * 4;
          *(u64_t*)&h_s[r * KP + k4] = tmp[k];
        }
      }
    }
    __syncthreads();

    const bool proj_on = (t >= 513);
    const int u = lane & 15, q = lane >> 4;
    if ((w < 4 && !last) || (w == 4 && proj_on)) {
      f32x4 acc0 = {0.f, 0.f, 0.f, 0.f};
      f32x4 acc1 = {0.f, 0.f, 0.f, 0.f};
      if (w < 4) {
        // acc init = bias + one-hot gather from W_ih
        float bv = bias_s[w * HHU + u];
        const int rowoff = (w * HHU + u) * WIHP;
#pragma unroll
        for (int r = 0; r < 4; ++r) acc0[r] = bv + bf2f(Wih_s[rowoff + idx_s[q * 4 + r]]);
#pragma unroll
        for (int r = 0; r < 4; ++r) acc1[r] = bv + bf2f(Wih_s[rowoff + idx_s[16 + q * 4 + r]]);
      }
      const ushort_t* bp = &Whh_s[(w * 16 + u) * KP + q * 8];
      const ushort_t* ap0 = &h_s[u * KP + q * 8];
      const ushort_t* ap1 = &h_s[(16 + u) * KP + q * 8];
#pragma unroll
      for (int kt = 0; kt < 16; ++kt) {
        bf16x8 bfr = *(const bf16x8*)(bp + kt * 32);
        bf16x8 af0 = *(const bf16x8*)(ap0 + kt * 32);
        bf16x8 af1 = *(const bf16x8*)(ap1 + kt * 32);
        acc0 = __builtin_amdgcn_mfma_f32_16x16x32_bf16(af0, bfr, acc0, 0, 0, 0);
        acc1 = __builtin_amdgcn_mfma_f32_16x16x32_bf16(af1, bfr, acc1, 0, 0, 0);
      }
      if (w < 4) {
#pragma unroll
        for (int r = 0; r < 4; ++r) {
          g_s[(w * BB + q * 4 + r) * 17 + u] = acc0[r];
          g_s[(w * BB + 16 + q * 4 + r) * 17 + u] = acc1[r];
        }
      } else if (u < 4) {
        const int ld = t - 513;  // logits step index 0..511
        float pbv = pb_s[u];
#pragma unroll
        for (int r = 0; r < 4; ++r) {
          logits[((size_t)ld * BDIM + bg * BB + q * 4 + r) * VDIM + hs * 4 + u] =
              f2bf(acc0[r] + pbv);
          logits[((size_t)ld * BDIM + bg * BB + 16 + q * 4 + r) * VDIM + hs * 4 + u] =
              f2bf(acc1[r] + pbv);
        }
      }
    }
    __syncthreads();

    if (!last) {
      if (tid < 128) {  // c/h update: 32 batches x 16 units, 4 units/thread
        const int b = tid >> 2, uq = tid & 3;
        ushort_t hv[4];
#pragma unroll
        for (int j = 0; j < 4; ++j) {
          const int uu = uq * 4 + j;
          float ig = g_s[(0 * BB + b) * 17 + uu];
          float fg = g_s[(1 * BB + b) * 17 + uu];
          float gg = g_s[(2 * BB + b) * 17 + uu];
          float og = g_s[(3 * BB + b) * 17 + uu];
          float co = c_s[b * 17 + uu];
          float cn = sigmoidf_(fg) * co + sigmoidf_(ig) * tanhf_(gg);
          c_s[b * 17 + uu] = cn;
          hv[j] = f2bf(sigmoidf_(og) * tanhf_(cn));
        }
        u64_t pk = (u64_t)hv[0] | ((u64_t)hv[1] << 16) | ((u64_t)hv[2] << 32) |
                   ((u64_t)hv[3] << 48);
        u64_t* dst = (u64_t*)(hbuf + ((size_t)((t + 1) & 1) * BDIM + bg * BB + b) * HDIM +
                              hs * HHU + uq * 4);
        __hip_atomic_store(dst, pk, __ATOMIC_RELAXED, __HIP_MEMORY_SCOPE_AGENT);
      }
      __syncthreads();  // s_waitcnt vmcnt(0): every wave's h stores are at the LLC
      if (tid == 0)
        __hip_atomic_store(&flags[bg * NHS + hs], (unsigned)(t + 1), __ATOMIC_RELAXED,
                           __HIP_MEMORY_SCOPE_AGENT);
    }
  }
}

__global__ void loss_kernel(const ushort_t* __restrict__ logits, const int* __restrict__ E,
                            float* __restrict__ partial) {
  const int t = blockIdx.x;   // 512
  const int b = threadIdx.x;  // 256
  const ushort_t* row = logits + ((size_t)t * BDIM + b) * VDIM;
  float mx = -3.0e38f;
  for (int k = 0; k < VDIM; ++k) mx = fmaxf(mx, bf2f(row[k]));
  float se = 0.f;
  for (int k = 0; k < VDIM; ++k) se += __expf(bf2f(row[k]) - mx);
  const int tgt = E[(size_t)b * (SDIM + 1) + t];
  float nll = (mx + __logf(se)) - bf2f(row[tgt]);
  float m = (tgt != 0) ? 1.f : 0.f;
  __shared__ float s1[BDIM];
  __shared__ float s0[BDIM];
  s1[b] = nll * m;
  s0[b] = m;
  __syncthreads();
  for (int s = 128; s > 0; s >>= 1) {
    if (b < s) {
      s1[b] += s1[b + s];
      s0[b] += s0[b + s];
    }
    __syncthreads();
  }
  if (b == 0) partial[t] = (s0[0] > 0.f) ? s1[0] / s0[0] : 0.f;
}

__global__ void reduce_kernel(const float* __restrict__ partial, float* __restrict__ out) {
  __shared__ float sm[SDIM];
  sm[threadIdx.x] = partial[threadIdx.x];
  __syncthreads();
  for (int s = 256; s > 0; s >>= 1) {
    if (threadIdx.x < s) sm[threadIdx.x] += sm[threadIdx.x + s];
    __syncthreads();
  }
  if (threadIdx.x == 0) out[0] = sm[0];
}

extern "C" void kernel_launch(void* const* d_in, const int* in_sizes, int n_in,
                              void* d_out, int out_size, void* d_ws, size_t ws_size,
                              hipStream_t stream) {
  const int* C_idx = (const int*)d_in[0];
  const int* E = (const int*)d_in[1];
  const float* eWih = (const float*)d_in[2];
  const float* eWhh = (const float*)d_in[3];
  const float* ebi = (const float*)d_in[4];
  const float* ebh = (const float*)d_in[5];
  const float* dWih = (const float*)d_in[6];
  const float* dWhh = (const float*)d_in[7];
  const float* dbi = (const float*)d_in[8];
  const float* dbh = (const float*)d_in[9];
  const float* pW = (const float*)d_in[10];
  const float* pb = (const float*)d_in[11];

  char* ws = (char*)d_ws;
  unsigned* flags = (unsigned*)ws;                             // 8*32*4 B (pad to 32768)
  ushort_t* hbuf = (ushort_t*)(ws + 32768);                    // 2*256*512*2   = 524288 B
  ushort_t* logits = (ushort_t*)(ws + 32768 + 524288);         // 512*256*128*2 = 32 MiB
  float* partial = (float*)(ws + 32768 + 524288 + 33554432);   // 512*4 B

  // zero flags + h double-buffer (h0 = c0 = 0); ws is poisoned 0xAA each call
  hipMemsetAsync(d_ws, 0, 32768 + 524288, stream);
  lstm_kernel<<<256, NT, 0, stream>>>(C_idx, E, eWih, eWhh, ebi, ebh, dWih, dWhh, dbi, dbh,
                                      pW, pb, flags, hbuf, logits);
  loss_kernel<<<512, 256, 0, stream>>>(logits, E, partial);
  reduce_kernel<<<1, 512, 0, stream>>>(partial, (float*)d_out);
}